// Round 1
// baseline (641.503 us; speedup 1.0000x reference)
//
#include <hip/hip_runtime.h>
#include <cstdint>
#include <cstddef>

using u16 = unsigned short;
using u32 = unsigned int;

typedef __bf16 bf16x8 __attribute__((ext_vector_type(8)));
typedef float f32x4 __attribute__((ext_vector_type(4)));

#define AS1 __attribute__((address_space(1)))
#define AS3 __attribute__((address_space(3)))

__device__ __forceinline__ void gload16(const void* g, void* l) {
  __builtin_amdgcn_global_load_lds((const AS1 u32*)g, (AS3 u32*)l, 16, 0, 0);
}

__device__ __forceinline__ u16 bf16bits(float f) {
  u32 u = __float_as_uint(f);
  u32 r = (u + 0x7fffu + ((u >> 16) & 1u)) >> 16;
  return (u16)r;
}

// ---------------------------------------------------------------------------
// Generic bf16 GEMM core: C[128,128] tile of A[M,K] * Bt[N,K]^T, BK=64.
// 256 threads = 4 waves (2x2), each wave 64x64 via 4x4 frags of 16x16x32 MFMA.
// LDS: A 128x128B, B 128x128B, XOR-swizzled 16B chunks (chunk ^= row&7),
// source-pre-swizzled so global_load_lds (linear dest) + swizzled ds_read match.
// ---------------------------------------------------------------------------
__device__ __forceinline__ void gemm_core(const u16* __restrict__ A,
                                          const u16* __restrict__ Bt,
                                          int K, int mb, int nb,
                                          char* smem, f32x4 (&acc)[4][4]) {
  const int tid = threadIdx.x;
  const int lane = tid & 63;
  const int w = tid >> 6;
  const int wr = w >> 1, wc = w & 1;
  char* As = smem;
  char* Bs = smem + 16384;

  const int trow = tid >> 3;                 // 0..31 (row within 32-row stripe)
  const int gsw = (tid & 7) ^ (trow & 7);    // pre-swizzled source chunk

  const u16* ga[4]; const u16* gb[4];
  char* la[4]; char* lb[4];
#pragma unroll
  for (int i = 0; i < 4; ++i) {
    int row = i * 32 + trow;
    ga[i] = A  + (size_t)(mb * 128 + row) * K + gsw * 8;
    gb[i] = Bt + (size_t)(nb * 128 + row) * K + gsw * 8;
    la[i] = As + i * 4096 + w * 1024;
    lb[i] = Bs + i * 4096 + w * 1024;
  }
#pragma unroll
  for (int i = 0; i < 4; ++i)
#pragma unroll
    for (int j = 0; j < 4; ++j)
      acc[i][j] = f32x4{0.f, 0.f, 0.f, 0.f};

  int aoff[2][4], boff[2][4];
#pragma unroll
  for (int kk = 0; kk < 2; ++kk)
#pragma unroll
    for (int t = 0; t < 4; ++t) {
      int ra = wr * 64 + t * 16 + (lane & 15);
      aoff[kk][t] = ra * 128 + (((kk * 4 + (lane >> 4)) ^ (ra & 7)) << 4);
      int rb = wc * 64 + t * 16 + (lane & 15);
      boff[kk][t] = rb * 128 + (((kk * 4 + (lane >> 4)) ^ (rb & 7)) << 4);
    }

  const int nk = K >> 6;
  for (int kt = 0; kt < nk; ++kt) {
#pragma unroll
    for (int i = 0; i < 4; ++i) gload16(ga[i], la[i]);
#pragma unroll
    for (int i = 0; i < 4; ++i) gload16(gb[i], lb[i]);
#pragma unroll
    for (int i = 0; i < 4; ++i) { ga[i] += 64; gb[i] += 64; }
    __syncthreads();
#pragma unroll
    for (int kk = 0; kk < 2; ++kk) {
      bf16x8 af[4], bfr[4];
#pragma unroll
      for (int t = 0; t < 4; ++t) af[t]  = *(const bf16x8*)(As + aoff[kk][t]);
#pragma unroll
      for (int t = 0; t < 4; ++t) bfr[t] = *(const bf16x8*)(Bs + boff[kk][t]);
#pragma unroll
      for (int i = 0; i < 4; ++i)
#pragma unroll
        for (int j = 0; j < 4; ++j)
          acc[i][j] = __builtin_amdgcn_mfma_f32_16x16x32_bf16(af[i], bfr[j], acc[i][j], 0, 0, 0);
    }
    __syncthreads();
  }
}

// ---------------------------------------------------------------------------
// Weight transpose + bf16 cast: W[K][N] f32 -> Wt[N][K] bf16
// ---------------------------------------------------------------------------
__global__ void wtrans(const float* __restrict__ W, u16* __restrict__ Wt, int K, int N) {
  int idx = blockIdx.x * 256 + threadIdx.x;
  if (idx < K * N) {
    int n = idx / K, k = idx - n * K;
    Wt[idx] = bf16bits(W[(size_t)k * N + n]);
  }
}

// ---------------------------------------------------------------------------
// LN1 fused with roll(-3,-3) + window partition gather.  One wave per out row.
// out row = win*49+tok, win = b*64+wi*8+wj, tok = r*7+c
// source = x[b, (wi*7+r+3)%56, (wj*7+c+3)%56, :]
// ---------------------------------------------------------------------------
__global__ __launch_bounds__(256) void ln1_win(const float* __restrict__ x,
                                               const float* __restrict__ g,
                                               const float* __restrict__ b,
                                               u16* __restrict__ xw) {
  const int lane = threadIdx.x & 63;
  const int w = threadIdx.x >> 6;
  const int row = blockIdx.x * 4 + w;
  const int win = row / 49, tok = row - win * 49;
  const int bimg = win >> 6, wloc = win & 63, wi = wloc >> 3, wj = wloc & 7;
  const int r = tok / 7, cc = tok - r * 7;
  const int ho = (wi * 7 + r + 3) % 56;
  const int wo = (wj * 7 + cc + 3) % 56;
  const float* src = x + ((size_t)bimg * 3136 + ho * 56 + wo) * 384;
  float v[6]; float s = 0.f, s2 = 0.f;
#pragma unroll
  for (int i = 0; i < 6; ++i) { float t = src[lane + i * 64]; v[i] = t; s += t; s2 += t * t; }
#pragma unroll
  for (int o = 1; o < 64; o <<= 1) { s += __shfl_xor(s, o); s2 += __shfl_xor(s2, o); }
  float mu = s * (1.f / 384.f);
  float rs = rsqrtf(s2 * (1.f / 384.f) - mu * mu + 1e-5f);
  u16* dst = xw + (size_t)row * 384;
#pragma unroll
  for (int i = 0; i < 6; ++i) {
    int c = lane + i * 64;
    dst[c] = bf16bits((v[i] - mu) * rs * g[c] + b[c]);
  }
}

// LN2: identity row mapping, reads x2 (f32, in d_out), writes bf16
__global__ __launch_bounds__(256) void ln2_kernel(const float* __restrict__ xin,
                                                  const float* __restrict__ g,
                                                  const float* __restrict__ b,
                                                  u16* __restrict__ h2) {
  const int lane = threadIdx.x & 63;
  const int w = threadIdx.x >> 6;
  const int row = blockIdx.x * 4 + w;
  const float* src = xin + (size_t)row * 384;
  float v[6]; float s = 0.f, s2 = 0.f;
#pragma unroll
  for (int i = 0; i < 6; ++i) { float t = src[lane + i * 64]; v[i] = t; s += t; s2 += t * t; }
#pragma unroll
  for (int o = 1; o < 64; o <<= 1) { s += __shfl_xor(s, o); s2 += __shfl_xor(s2, o); }
  float mu = s * (1.f / 384.f);
  float rs = rsqrtf(s2 * (1.f / 384.f) - mu * mu + 1e-5f);
  u16* dst = h2 + (size_t)row * 384;
#pragma unroll
  for (int i = 0; i < 6; ++i) {
    int c = lane + i * 64;
    dst[c] = bf16bits((v[i] - mu) * rs * g[c] + b[c]);
  }
}

// ---------------------------------------------------------------------------
// QKV GEMM: [50176,384]x[384,1152] + bias; scatter to q/k/v [win][head][49][32]
// q pre-scaled by 1/sqrt(32).
// ---------------------------------------------------------------------------
__global__ __launch_bounds__(256) void qkv_gemm(const u16* __restrict__ A,
                                                const u16* __restrict__ Bt,
                                                const float* __restrict__ bias,
                                                u16* __restrict__ qo,
                                                u16* __restrict__ ko,
                                                u16* __restrict__ vo) {
  __shared__ char smem[32768];
  const int mb = blockIdx.x % 392, nb = blockIdx.x / 392;
  f32x4 acc[4][4];
  gemm_core(A, Bt, 384, mb, nb, smem, acc);
  const int lane = threadIdx.x & 63, w = threadIdx.x >> 6;
  const int r0 = mb * 128 + (w >> 1) * 64 + ((lane >> 4) << 2);
  const int c0 = nb * 128 + (w & 1) * 64 + (lane & 15);
#pragma unroll
  for (int i = 0; i < 4; ++i)
#pragma unroll
    for (int j = 0; j < 4; ++j)
#pragma unroll
      for (int e = 0; e < 4; ++e) {
        int row = r0 + i * 16 + e;
        int col = c0 + j * 16;
        float v = acc[i][j][e] + bias[col];
        int which = col >= 768 ? 2 : (col >= 384 ? 1 : 0);
        int rem = col - which * 384;
        int head = rem >> 5, d = rem & 31;
        int wn = row / 49, tok = row - wn * 49;
        size_t off = ((size_t)(wn * 12 + head) * 49 + tok) * 32 + d;
        if (which == 0)      qo[off] = bf16bits(v * 0.17677669529663687f);
        else if (which == 1) ko[off] = bf16bits(v);
        else                 vo[off] = bf16bits(v);
      }
}

// ---------------------------------------------------------------------------
// Attention: one wave per (window, head).  LDS: q/k padded [64][40] bf16,
// vt [32][72] bf16, P [64][72] bf16.  Bias/mask computed analytically.
// ---------------------------------------------------------------------------
__global__ __launch_bounds__(64) void attn_kernel(const u16* __restrict__ qb,
                                                  const u16* __restrict__ kb,
                                                  const u16* __restrict__ vb,
                                                  const float* __restrict__ rpb,
                                                  u16* __restrict__ ob) {
  __shared__ char smem[24064];
  char* qs  = smem;            // 64 x 80B
  char* ks  = smem + 5120;     // 64 x 80B
  char* vts = smem + 10240;    // 32 x 144B
  char* ps  = smem + 14848;    // 64 x 144B
  const int lane = threadIdx.x;
  const int bx = blockIdx.x;
  const int win = bx / 12, head = bx - win * 12;

  // zero pad rows of q/k (rows 49..63) and all of vt
  for (int i = lane; i < 300; i += 64) {
    ((u32*)qs)[980 + i] = 0;
    ((u32*)ks)[980 + i] = 0;
  }
  for (int i = lane; i < 1152; i += 64) ((u32*)vts)[i] = 0;
  __syncthreads();

  const size_t base = (size_t)(win * 12 + head) * 1568;
  const uint4* qg = (const uint4*)(qb + base);
  const uint4* kg = (const uint4*)(kb + base);
#pragma unroll
  for (int it = 0; it < 4; ++it) {
    int c = lane + it * 64;
    if (c < 196) {
      uint4 tq = qg[c]; uint4 tk = kg[c];
      int tok = c >> 2, jj = c & 3;
      *(uint4*)(qs + tok * 80 + jj * 16) = tq;
      *(uint4*)(ks + tok * 80 + jj * 16) = tk;
    }
  }
  const u16* vg = vb + base;
#pragma unroll
  for (int it = 0; it < 4; ++it) {
    int c = lane + it * 64;
    if (c < 196) {
      int tok = c >> 2, d0 = (c & 3) * 8;
      union { uint4 v; u16 h[8]; } u;
      u.v = *(const uint4*)(vg + c * 8);
#pragma unroll
      for (int jj = 0; jj < 8; ++jj)
        *(u16*)(vts + (d0 + jj) * 144 + tok * 2) = u.h[jj];
    }
  }
  __syncthreads();

  // S = q k^T  (M=64,N=64,K=32)
  f32x4 s[4][4];
#pragma unroll
  for (int i = 0; i < 4; ++i)
#pragma unroll
    for (int j = 0; j < 4; ++j) s[i][j] = f32x4{0.f, 0.f, 0.f, 0.f};
  const int rsel = lane & 15;
  const int koff = (lane >> 4) * 16;
  {
    bf16x8 aq[4], bk[4];
#pragma unroll
    for (int t = 0; t < 4; ++t) {
      aq[t] = *(const bf16x8*)(qs + (t * 16 + rsel) * 80 + koff);
      bk[t] = *(const bf16x8*)(ks + (t * 16 + rsel) * 80 + koff);
    }
#pragma unroll
    for (int i = 0; i < 4; ++i)
#pragma unroll
      for (int j = 0; j < 4; ++j)
        s[i][j] = __builtin_amdgcn_mfma_f32_16x16x32_bf16(aq[i], bk[j], s[i][j], 0, 0, 0);
  }

  // bias + shift-mask + wave-parallel softmax; write P (bf16) to LDS
  const int wloc = win & 63, wi = wloc >> 3, wj = wloc & 7;
  const int rowsub = (lane >> 4) << 2;
#pragma unroll
  for (int i = 0; i < 4; ++i) {
#pragma unroll
    for (int e = 0; e < 4; ++e) {
      int row = i * 16 + rowsub + e;
      float v[4];
#pragma unroll
      for (int j = 0; j < 4; ++j) {
        int col = j * 16 + rsel;
        float val = s[i][j][e];
        if (col >= 49) val = -1e30f;
        else if (row < 49) {
          int qr = row / 7, qc = row - qr * 7;
          int kr = col / 7, kc = col - kr * 7;
          float bias = rpb[((qr - kr + 6) * 13 + (qc - kc + 6)) * 12 + head];
          int ph = wi * 7 + qr, pw = wj * 7 + qc;
          int kh = wi * 7 + kr, kw = wj * 7 + kc;
          int idq = (ph < 49 ? 0 : (ph < 53 ? 3 : 6)) + (pw < 49 ? 0 : (pw < 53 ? 1 : 2));
          int idk = (kh < 49 ? 0 : (kh < 53 ? 3 : 6)) + (kw < 49 ? 0 : (kw < 53 ? 1 : 2));
          val += bias + (idq == idk ? 0.f : -100.f);
        }
        v[j] = val;
      }
      float m = fmaxf(fmaxf(v[0], v[1]), fmaxf(v[2], v[3]));
#pragma unroll
      for (int o = 1; o < 16; o <<= 1) m = fmaxf(m, __shfl_xor(m, o));
      float p[4]; float sum = 0.f;
#pragma unroll
      for (int j = 0; j < 4; ++j) { p[j] = __expf(v[j] - m); sum += p[j]; }
#pragma unroll
      for (int o = 1; o < 16; o <<= 1) sum += __shfl_xor(sum, o);
      float inv = 1.f / sum;
#pragma unroll
      for (int j = 0; j < 4; ++j)
        *(u16*)(ps + row * 144 + (j * 16 + rsel) * 2) = bf16bits(p[j] * inv);
    }
  }
  __syncthreads();

  // O = P V   (M=64, N=32, K=64)
  f32x4 o[4][2];
#pragma unroll
  for (int i = 0; i < 4; ++i)
#pragma unroll
    for (int j = 0; j < 2; ++j) o[i][j] = f32x4{0.f, 0.f, 0.f, 0.f};
#pragma unroll
  for (int kk = 0; kk < 2; ++kk) {
    bf16x8 ap[4], bv[2];
#pragma unroll
    for (int t = 0; t < 4; ++t)
      ap[t] = *(const bf16x8*)(ps + (t * 16 + rsel) * 144 + kk * 64 + koff);
#pragma unroll
    for (int t = 0; t < 2; ++t)
      bv[t] = *(const bf16x8*)(vts + (t * 16 + rsel) * 144 + kk * 64 + koff);
#pragma unroll
    for (int i = 0; i < 4; ++i)
#pragma unroll
      for (int j = 0; j < 2; ++j)
        o[i][j] = __builtin_amdgcn_mfma_f32_16x16x32_bf16(ap[i], bv[j], o[i][j], 0, 0, 0);
  }

  u16* obase = ob + (size_t)win * 49 * 384 + head * 32;
#pragma unroll
  for (int i = 0; i < 4; ++i)
#pragma unroll
    for (int j = 0; j < 2; ++j)
#pragma unroll
      for (int e = 0; e < 4; ++e) {
        int tok = i * 16 + rowsub + e;
        if (tok < 49)
          obase[(size_t)tok * 384 + j * 16 + rsel] = bf16bits(o[i][j][e]);
      }
}

// ---------------------------------------------------------------------------
// proj GEMM: [50176,384]x[384,384] + bias; window-reverse + roll-back scatter
// + shortcut add -> x2 (f32, in d_out)
// ---------------------------------------------------------------------------
__global__ __launch_bounds__(256) void proj_gemm(const u16* __restrict__ A,
                                                 const u16* __restrict__ Bt,
                                                 const float* __restrict__ bias,
                                                 const float* __restrict__ xres,
                                                 float* __restrict__ out) {
  __shared__ char smem[32768];
  const int mb = blockIdx.x % 392, nb = blockIdx.x / 392;
  f32x4 acc[4][4];
  gemm_core(A, Bt, 384, mb, nb, smem, acc);
  const int lane = threadIdx.x & 63, w = threadIdx.x >> 6;
  const int r0 = mb * 128 + (w >> 1) * 64 + ((lane >> 4) << 2);
  const int c0 = nb * 128 + (w & 1) * 64 + (lane & 15);
#pragma unroll
  for (int i = 0; i < 4; ++i)
#pragma unroll
    for (int j = 0; j < 4; ++j)
#pragma unroll
      for (int e = 0; e < 4; ++e) {
        int row = r0 + i * 16 + e;
        int col = c0 + j * 16;
        float v = acc[i][j][e] + bias[col];
        int wn = row / 49, tok = row - wn * 49;
        int bimg = wn >> 6, wloc = wn & 63, wi = wloc >> 3, wj = wloc & 7;
        int r = tok / 7, cc = tok - r * 7;
        int ho = (wi * 7 + r + 3) % 56;
        int wo = (wj * 7 + cc + 3) % 56;
        size_t gi = ((size_t)bimg * 3136 + ho * 56 + wo) * 384 + col;
        out[gi] = v + xres[gi];
      }
}

// fc1: [25088,384]x[384,1536] + bias + exact GELU -> bf16
__global__ __launch_bounds__(256) void fc1_gemm(const u16* __restrict__ A,
                                                const u16* __restrict__ Bt,
                                                const float* __restrict__ bias,
                                                u16* __restrict__ h3) {
  __shared__ char smem[32768];
  const int mb = blockIdx.x % 196, nb = blockIdx.x / 196;
  f32x4 acc[4][4];
  gemm_core(A, Bt, 384, mb, nb, smem, acc);
  const int lane = threadIdx.x & 63, w = threadIdx.x >> 6;
  const int r0 = mb * 128 + (w >> 1) * 64 + ((lane >> 4) << 2);
  const int c0 = nb * 128 + (w & 1) * 64 + (lane & 15);
#pragma unroll
  for (int i = 0; i < 4; ++i)
#pragma unroll
    for (int j = 0; j < 4; ++j)
#pragma unroll
      for (int e = 0; e < 4; ++e) {
        int row = r0 + i * 16 + e;
        int col = c0 + j * 16;
        float v = acc[i][j][e] + bias[col];
        float gl = 0.5f * v * (1.f + erff(v * 0.70710678118654752f));
        h3[(size_t)row * 1536 + col] = bf16bits(gl);
      }
}

// fc2: [25088,1536]x[1536,384] + bias; out += mlp
__global__ __launch_bounds__(256) void fc2_gemm(const u16* __restrict__ A,
                                                const u16* __restrict__ Bt,
                                                const float* __restrict__ bias,
                                                float* __restrict__ out,
                                                int row_base) {
  __shared__ char smem[32768];
  const int mb = blockIdx.x % 196, nb = blockIdx.x / 196;
  f32x4 acc[4][4];
  gemm_core(A, Bt, 1536, mb, nb, smem, acc);
  const int lane = threadIdx.x & 63, w = threadIdx.x >> 6;
  const int r0 = mb * 128 + (w >> 1) * 64 + ((lane >> 4) << 2);
  const int c0 = nb * 128 + (w & 1) * 64 + (lane & 15);
#pragma unroll
  for (int i = 0; i < 4; ++i)
#pragma unroll
    for (int j = 0; j < 4; ++j)
#pragma unroll
      for (int e = 0; e < 4; ++e) {
        int row = r0 + i * 16 + e;
        int col = c0 + j * 16;
        float v = acc[i][j][e] + bias[col];
        size_t gi = (size_t)(row_base + row) * 384 + col;
        out[gi] += v;
      }
}

// ---------------------------------------------------------------------------
extern "C" void kernel_launch(void* const* d_in, const int* in_sizes, int n_in,
                              void* d_out, int out_size, void* d_ws, size_t ws_size,
                              hipStream_t stream) {
  const float* x      = (const float*)d_in[0];
  const float* n1g    = (const float*)d_in[1];
  const float* n1b    = (const float*)d_in[2];
  const float* qkv_w  = (const float*)d_in[3];
  const float* qkv_b  = (const float*)d_in[4];
  const float* rpb    = (const float*)d_in[5];
  const float* proj_w = (const float*)d_in[6];
  const float* proj_b = (const float*)d_in[7];
  const float* n2g    = (const float*)d_in[8];
  const float* n2b    = (const float*)d_in[9];
  const float* fc1_w  = (const float*)d_in[10];
  const float* fc1_b  = (const float*)d_in[11];
  const float* fc2_w  = (const float*)d_in[12];
  const float* fc2_b  = (const float*)d_in[13];
  float* out = (float*)d_out;

  char* ws = (char*)d_ws;
  const size_t S = (size_t)50176 * 384 * 2;   // 38.5 MB (one bf16 [50176,384])
  u16* xw  = (u16*)ws;                        // LN1 out; later reused as attn output o
  u16* qb  = (u16*)(ws + S);
  u16* kb  = (u16*)(ws + 2 * S);
  u16* vb  = (u16*)(ws + 3 * S);
  u16* h2  = (u16*)(ws + 4 * S);
  u16* h3  = (u16*)(ws + S);                  // aliases q+k (dead after attention)
  u16* wqt  = (u16*)(ws + 5 * S);             // transposed bf16 weights (~3.5 MB)
  u16* wpt  = wqt  + 384 * 1152;
  u16* wf1t = wpt  + 384 * 384;
  u16* wf2t = wf1t + 384 * 1536;

  wtrans<<<(384 * 1152 + 255) / 256, 256, 0, stream>>>(qkv_w, wqt, 384, 1152);
  wtrans<<<(384 * 384  + 255) / 256, 256, 0, stream>>>(proj_w, wpt, 384, 384);
  wtrans<<<(384 * 1536 + 255) / 256, 256, 0, stream>>>(fc1_w, wf1t, 384, 1536);
  wtrans<<<(1536 * 384 + 255) / 256, 256, 0, stream>>>(fc2_w, wf2t, 1536, 384);

  ln1_win<<<12544, 256, 0, stream>>>(x, n1g, n1b, xw);
  qkv_gemm<<<392 * 9, 256, 0, stream>>>(xw, wqt, qkv_b, qb, kb, vb);
  attn_kernel<<<12288, 64, 0, stream>>>(qb, kb, vb, rpb, xw);
  proj_gemm<<<392 * 3, 256, 0, stream>>>(xw, wpt, proj_b, x, out);
  ln2_kernel<<<12544, 256, 0, stream>>>(out, n2g, n2b, h2);
  for (int ch = 0; ch < 2; ++ch) {
    fc1_gemm<<<196 * 12, 256, 0, stream>>>(h2 + (size_t)ch * 25088 * 384, wf1t, fc1_b, h3);
    fc2_gemm<<<196 * 3, 256, 0, stream>>>(h3, wf2t, fc2_b, out, ch * 25088);
  }
}

// Round 2
// 559.183 us; speedup vs baseline: 1.1472x; 1.1472x over previous
//
#include <hip/hip_runtime.h>
#include <cstdint>
#include <cstddef>

using u16 = unsigned short;
using u32 = unsigned int;

typedef __bf16 bf16x8 __attribute__((ext_vector_type(8)));
typedef float f32x4 __attribute__((ext_vector_type(4)));

#define AS1 __attribute__((address_space(1)))
#define AS3 __attribute__((address_space(3)))

__device__ __forceinline__ void gload16(const void* g, void* l) {
  __builtin_amdgcn_global_load_lds((const AS1 u32*)g, (AS3 u32*)l, 16, 0, 0);
}

__device__ __forceinline__ u16 bf16bits(float f) {
  u32 u = __float_as_uint(f);
  u32 r = (u + 0x7fffu + ((u >> 16) & 1u)) >> 16;
  return (u16)r;
}

// ---------------------------------------------------------------------------
// Generic bf16 GEMM core: C[128,128] tile of A[M,K] * Bt[N,K]^T, BK=64.
// 256 threads = 4 waves (2x2), each wave 64x64 via 4x4 frags of 16x16x32 MFMA.
// ---------------------------------------------------------------------------
__device__ __forceinline__ void gemm_core(const u16* __restrict__ A,
                                          const u16* __restrict__ Bt,
                                          int K, int mb, int nb,
                                          char* smem, f32x4 (&acc)[4][4]) {
  const int tid = threadIdx.x;
  const int lane = tid & 63;
  const int w = tid >> 6;
  const int wr = w >> 1, wc = w & 1;
  char* As = smem;
  char* Bs = smem + 16384;

  const int trow = tid >> 3;                 // 0..31 (row within 32-row stripe)
  const int gsw = (tid & 7) ^ (trow & 7);    // pre-swizzled source chunk

  const u16* ga[4]; const u16* gb[4];
  char* la[4]; char* lb[4];
#pragma unroll
  for (int i = 0; i < 4; ++i) {
    int row = i * 32 + trow;
    ga[i] = A  + (size_t)(mb * 128 + row) * K + gsw * 8;
    gb[i] = Bt + (size_t)(nb * 128 + row) * K + gsw * 8;
    la[i] = As + i * 4096 + w * 1024;
    lb[i] = Bs + i * 4096 + w * 1024;
  }
#pragma unroll
  for (int i = 0; i < 4; ++i)
#pragma unroll
    for (int j = 0; j < 4; ++j)
      acc[i][j] = f32x4{0.f, 0.f, 0.f, 0.f};

  int aoff[2][4], boff[2][4];
#pragma unroll
  for (int kk = 0; kk < 2; ++kk)
#pragma unroll
    for (int t = 0; t < 4; ++t) {
      int ra = wr * 64 + t * 16 + (lane & 15);
      aoff[kk][t] = ra * 128 + (((kk * 4 + (lane >> 4)) ^ (ra & 7)) << 4);
      int rb = wc * 64 + t * 16 + (lane & 15);
      boff[kk][t] = rb * 128 + (((kk * 4 + (lane >> 4)) ^ (rb & 7)) << 4);
    }

  const int nk = K >> 6;
  for (int kt = 0; kt < nk; ++kt) {
#pragma unroll
    for (int i = 0; i < 4; ++i) gload16(ga[i], la[i]);
#pragma unroll
    for (int i = 0; i < 4; ++i) gload16(gb[i], lb[i]);
#pragma unroll
    for (int i = 0; i < 4; ++i) { ga[i] += 64; gb[i] += 64; }
    __syncthreads();
#pragma unroll
    for (int kk = 0; kk < 2; ++kk) {
      bf16x8 af[4], bfr[4];
#pragma unroll
      for (int t = 0; t < 4; ++t) af[t]  = *(const bf16x8*)(As + aoff[kk][t]);
#pragma unroll
      for (int t = 0; t < 4; ++t) bfr[t] = *(const bf16x8*)(Bs + boff[kk][t]);
#pragma unroll
      for (int i = 0; i < 4; ++i)
#pragma unroll
        for (int j = 0; j < 4; ++j)
          acc[i][j] = __builtin_amdgcn_mfma_f32_16x16x32_bf16(af[i], bfr[j], acc[i][j], 0, 0, 0);
    }
    __syncthreads();
  }
}

// ---------------------------------------------------------------------------
// Weight transpose + bf16 cast: W[K][N] f32 -> Wt[N][K] bf16
// ---------------------------------------------------------------------------
__global__ void wtrans(const float* __restrict__ W, u16* __restrict__ Wt, int K, int N) {
  int idx = blockIdx.x * 256 + threadIdx.x;
  if (idx < K * N) {
    int n = idx / K, k = idx - n * K;
    Wt[idx] = bf16bits(W[(size_t)k * N + n]);
  }
}

// ---------------------------------------------------------------------------
// Fused bias+mask table: bt[cls][head][row][col], 4*12*64*64 f32.
// cls = (wi==7)*2 + (wj==7).  rows/cols >= 49 -> -1e30.
// ---------------------------------------------------------------------------
__global__ void gen_bias(const float* __restrict__ rpb, float* __restrict__ bt) {
  int idx = blockIdx.x * 256 + threadIdx.x;
  if (idx >= 4 * 12 * 4096) return;
  int col = idx & 63, row = (idx >> 6) & 63;
  int rest = idx >> 12;
  int h = rest % 12, cls = rest / 12;
  float v;
  if (row >= 49 || col >= 49) {
    v = -1e30f;
  } else {
    int qr = row / 7, qc = row - qr * 7;
    int kr = col / 7, kc = col - kr * 7;
    v = rpb[((qr - kr + 6) * 13 + (qc - kc + 6)) * 12 + h];
    bool wi7 = (cls & 2) != 0, wj7 = (cls & 1) != 0;
    int idq = (wi7 ? (qr < 4 ? 3 : 6) : 0) + (wj7 ? (qc < 4 ? 1 : 2) : 0);
    int idk = (wi7 ? (kr < 4 ? 3 : 6) : 0) + (wj7 ? (kc < 4 ? 1 : 2) : 0);
    if (idq != idk) v += -100.f;
  }
  bt[idx] = v;
}

// ---------------------------------------------------------------------------
// LN1 fused with roll(-3,-3) + window partition gather.  One wave per out row.
// ---------------------------------------------------------------------------
__global__ __launch_bounds__(256) void ln1_win(const float* __restrict__ x,
                                               const float* __restrict__ g,
                                               const float* __restrict__ b,
                                               u16* __restrict__ xw) {
  const int lane = threadIdx.x & 63;
  const int w = threadIdx.x >> 6;
  const int row = blockIdx.x * 4 + w;
  const int win = row / 49, tok = row - win * 49;
  const int bimg = win >> 6, wloc = win & 63, wi = wloc >> 3, wj = wloc & 7;
  const int r = tok / 7, cc = tok - r * 7;
  const int ho = (wi * 7 + r + 3) % 56;
  const int wo = (wj * 7 + cc + 3) % 56;
  const float* src = x + ((size_t)bimg * 3136 + ho * 56 + wo) * 384;
  float v[6]; float s = 0.f, s2 = 0.f;
#pragma unroll
  for (int i = 0; i < 6; ++i) { float t = src[lane + i * 64]; v[i] = t; s += t; s2 += t * t; }
#pragma unroll
  for (int o = 1; o < 64; o <<= 1) { s += __shfl_xor(s, o); s2 += __shfl_xor(s2, o); }
  float mu = s * (1.f / 384.f);
  float rs = rsqrtf(s2 * (1.f / 384.f) - mu * mu + 1e-5f);
  u16* dst = xw + (size_t)row * 384;
#pragma unroll
  for (int i = 0; i < 6; ++i) {
    int c = lane + i * 64;
    dst[c] = bf16bits((v[i] - mu) * rs * g[c] + b[c]);
  }
}

// LN2: identity row mapping, reads x2 (f32, in d_out), writes bf16
__global__ __launch_bounds__(256) void ln2_kernel(const float* __restrict__ xin,
                                                  const float* __restrict__ g,
                                                  const float* __restrict__ b,
                                                  u16* __restrict__ h2) {
  const int lane = threadIdx.x & 63;
  const int w = threadIdx.x >> 6;
  const int row = blockIdx.x * 4 + w;
  const float* src = xin + (size_t)row * 384;
  float v[6]; float s = 0.f, s2 = 0.f;
#pragma unroll
  for (int i = 0; i < 6; ++i) { float t = src[lane + i * 64]; v[i] = t; s += t; s2 += t * t; }
#pragma unroll
  for (int o = 1; o < 64; o <<= 1) { s += __shfl_xor(s, o); s2 += __shfl_xor(s2, o); }
  float mu = s * (1.f / 384.f);
  float rs = rsqrtf(s2 * (1.f / 384.f) - mu * mu + 1e-5f);
  u16* dst = h2 + (size_t)row * 384;
#pragma unroll
  for (int i = 0; i < 6; ++i) {
    int c = lane + i * 64;
    dst[c] = bf16bits((v[i] - mu) * rs * g[c] + b[c]);
  }
}

// ---------------------------------------------------------------------------
// QKV GEMM: [50176,384]x[384,1152] + bias; scatter to q/k/v [win][head][49][32]
// ---------------------------------------------------------------------------
__global__ __launch_bounds__(256) void qkv_gemm(const u16* __restrict__ A,
                                                const u16* __restrict__ Bt,
                                                const float* __restrict__ bias,
                                                u16* __restrict__ qo,
                                                u16* __restrict__ ko,
                                                u16* __restrict__ vo) {
  __shared__ char smem[32768];
  const int mb = blockIdx.x % 392, nb = blockIdx.x / 392;
  f32x4 acc[4][4];
  gemm_core(A, Bt, 384, mb, nb, smem, acc);
  const int lane = threadIdx.x & 63, w = threadIdx.x >> 6;
  const int r0 = mb * 128 + (w >> 1) * 64 + ((lane >> 4) << 2);
  const int c0 = nb * 128 + (w & 1) * 64 + (lane & 15);
#pragma unroll
  for (int i = 0; i < 4; ++i)
#pragma unroll
    for (int j = 0; j < 4; ++j)
#pragma unroll
      for (int e = 0; e < 4; ++e) {
        int row = r0 + i * 16 + e;
        int col = c0 + j * 16;
        float v = acc[i][j][e] + bias[col];
        int which = col >= 768 ? 2 : (col >= 384 ? 1 : 0);
        int rem = col - which * 384;
        int head = rem >> 5, d = rem & 31;
        int wn = row / 49, tok = row - wn * 49;
        size_t off = ((size_t)(wn * 12 + head) * 49 + tok) * 32 + d;
        if (which == 0)      qo[off] = bf16bits(v * 0.17677669529663687f);
        else if (which == 1) ko[off] = bf16bits(v);
        else                 vo[off] = bf16bits(v);
      }
}

// ---------------------------------------------------------------------------
// Attention v2: 128 threads = 2 independent waves, each one (win,head).
// No __syncthreads (wave-private LDS slices).  Q/K fragments direct from
// global (predicated).  Bias+mask via precomputed table.  LDS per wave:
// vt [32][136B] + P [64][136B] = 12.75KB -> 6 blocks/CU = 12 waves/CU.
// ---------------------------------------------------------------------------
__global__ __launch_bounds__(128, 3) void attn2(const u16* __restrict__ qb,
                                                const u16* __restrict__ kb,
                                                const u16* __restrict__ vb,
                                                const float* __restrict__ bt,
                                                u16* __restrict__ ob) {
  __shared__ char smem[26112];
  const int wv = threadIdx.x >> 6, lane = threadIdx.x & 63;
  char* vts = smem + wv * 13056;          // [32 d][136B]
  char* ps  = smem + wv * 13056 + 4352;   // [64 q][136B]
  const int p = blockIdx.x * 2 + wv;
  const int win = p / 12, head = p - win * 12;
  const int wloc = win & 63, wi = wloc >> 3, wj = wloc & 7;
  const int cls = ((wi == 7) ? 2 : 0) + ((wj == 7) ? 1 : 0);

  // zero vt (so P*0 stays clean for tok>=49)
#pragma unroll
  for (int i = 0; i < 17; ++i) ((u32*)vts)[lane + i * 64] = 0;

  const size_t base = (size_t)p * 1568;
  // V transpose into LDS: vt[d][tok]
  const u16* vg = vb + base;
#pragma unroll
  for (int it = 0; it < 4; ++it) {
    int c = lane + it * 64;
    if (c < 196) {
      int tok = c >> 2, d0 = (c & 3) * 8;
      union { uint4 v; u16 h[8]; } u;
      u.v = *(const uint4*)(vg + c * 8);
#pragma unroll
      for (int jj = 0; jj < 8; ++jj)
        *(u16*)(vts + (d0 + jj) * 136 + tok * 2) = u.h[jj];
    }
  }

  const int rsel = lane & 15;
  const int ksub = lane >> 4;
  // Q/K fragments direct from global, predicated
  const u16* qg = qb + base;
  const u16* kg = kb + base;
  bf16x8 aq[4], bk[4];
#pragma unroll
  for (int t = 0; t < 4; ++t) {
    int row = t * 16 + rsel;
    union { uint4 u; bf16x8 v; } rq, rk;
    if (row < 49) {
      rq.u = *(const uint4*)(qg + row * 32 + ksub * 8);
      rk.u = *(const uint4*)(kg + row * 32 + ksub * 8);
    } else {
      rq.u = uint4{0, 0, 0, 0};
      rk.u = uint4{0, 0, 0, 0};
    }
    aq[t] = rq.v; bk[t] = rk.v;
  }

  // S = q k^T
  f32x4 s[4][4];
#pragma unroll
  for (int i = 0; i < 4; ++i)
#pragma unroll
    for (int j = 0; j < 4; ++j) s[i][j] = f32x4{0.f, 0.f, 0.f, 0.f};
#pragma unroll
  for (int i = 0; i < 4; ++i)
#pragma unroll
    for (int j = 0; j < 4; ++j)
      s[i][j] = __builtin_amdgcn_mfma_f32_16x16x32_bf16(aq[i], bk[j], s[i][j], 0, 0, 0);

  // softmax with fused bias+mask table
  const float* tb = bt + ((size_t)(cls * 12 + head) << 12);
  const int rowsub = ksub << 2;
#pragma unroll
  for (int i = 0; i < 4; ++i) {
    float bl[4][4];
#pragma unroll
    for (int e = 0; e < 4; ++e) {
      int row = i * 16 + rowsub + e;
#pragma unroll
      for (int j = 0; j < 4; ++j) bl[e][j] = tb[row * 64 + j * 16 + rsel];
    }
#pragma unroll
    for (int e = 0; e < 4; ++e) {
      int row = i * 16 + rowsub + e;
      float v[4];
#pragma unroll
      for (int j = 0; j < 4; ++j) v[j] = s[i][j][e] + bl[e][j];
      float m = fmaxf(fmaxf(v[0], v[1]), fmaxf(v[2], v[3]));
#pragma unroll
      for (int o = 1; o < 16; o <<= 1) m = fmaxf(m, __shfl_xor(m, o));
      float pr[4]; float sum = 0.f;
#pragma unroll
      for (int j = 0; j < 4; ++j) { pr[j] = __expf(v[j] - m); sum += pr[j]; }
#pragma unroll
      for (int o = 1; o < 16; o <<= 1) sum += __shfl_xor(sum, o);
      float inv = 1.f / sum;
#pragma unroll
      for (int j = 0; j < 4; ++j)
        *(u16*)(ps + row * 136 + (j * 16 + rsel) * 2) = bf16bits(pr[j] * inv);
    }
  }

  // O = P V
  f32x4 o[4][2];
#pragma unroll
  for (int i = 0; i < 4; ++i)
#pragma unroll
    for (int j = 0; j < 2; ++j) o[i][j] = f32x4{0.f, 0.f, 0.f, 0.f};
#pragma unroll
  for (int kk = 0; kk < 2; ++kk) {
    bf16x8 ap[4], bv[2];
#pragma unroll
    for (int t = 0; t < 4; ++t)
      ap[t] = *(const bf16x8*)(ps + (t * 16 + rsel) * 136 + kk * 64 + ksub * 16);
#pragma unroll
    for (int t = 0; t < 2; ++t)
      bv[t] = *(const bf16x8*)(vts + (t * 16 + rsel) * 136 + kk * 64 + ksub * 16);
#pragma unroll
    for (int i = 0; i < 4; ++i)
#pragma unroll
      for (int j = 0; j < 2; ++j)
        o[i][j] = __builtin_amdgcn_mfma_f32_16x16x32_bf16(ap[i], bv[j], o[i][j], 0, 0, 0);
  }

  u16* obase = ob + (size_t)win * 49 * 384 + head * 32;
#pragma unroll
  for (int i = 0; i < 4; ++i)
#pragma unroll
    for (int j = 0; j < 2; ++j)
#pragma unroll
      for (int e = 0; e < 4; ++e) {
        int tok = i * 16 + rowsub + e;
        if (tok < 49)
          obase[(size_t)tok * 384 + j * 16 + rsel] = bf16bits(o[i][j][e]);
      }
}

// ---------------------------------------------------------------------------
// proj GEMM: [50176,384]x[384,384] + bias; window-reverse + roll-back scatter
// + shortcut add -> x2 (f32, in d_out)
// ---------------------------------------------------------------------------
__global__ __launch_bounds__(256) void proj_gemm(const u16* __restrict__ A,
                                                 const u16* __restrict__ Bt,
                                                 const float* __restrict__ bias,
                                                 const float* __restrict__ xres,
                                                 float* __restrict__ out) {
  __shared__ char smem[32768];
  const int mb = blockIdx.x % 392, nb = blockIdx.x / 392;
  f32x4 acc[4][4];
  gemm_core(A, Bt, 384, mb, nb, smem, acc);
  const int lane = threadIdx.x & 63, w = threadIdx.x >> 6;
  const int r0 = mb * 128 + (w >> 1) * 64 + ((lane >> 4) << 2);
  const int c0 = nb * 128 + (w & 1) * 64 + (lane & 15);
#pragma unroll
  for (int i = 0; i < 4; ++i)
#pragma unroll
    for (int j = 0; j < 4; ++j)
#pragma unroll
      for (int e = 0; e < 4; ++e) {
        int row = r0 + i * 16 + e;
        int col = c0 + j * 16;
        float v = acc[i][j][e] + bias[col];
        int wn = row / 49, tok = row - wn * 49;
        int bimg = wn >> 6, wloc = wn & 63, wi = wloc >> 3, wj = wloc & 7;
        int r = tok / 7, cc = tok - r * 7;
        int ho = (wi * 7 + r + 3) % 56;
        int wo = (wj * 7 + cc + 3) % 56;
        size_t gi = ((size_t)bimg * 3136 + ho * 56 + wo) * 384 + col;
        out[gi] = v + xres[gi];
      }
}

// fc1: [25088,384]x[384,1536] + bias + exact GELU -> bf16
__global__ __launch_bounds__(256) void fc1_gemm(const u16* __restrict__ A,
                                                const u16* __restrict__ Bt,
                                                const float* __restrict__ bias,
                                                u16* __restrict__ h3) {
  __shared__ char smem[32768];
  const int mb = blockIdx.x % 196, nb = blockIdx.x / 196;
  f32x4 acc[4][4];
  gemm_core(A, Bt, 384, mb, nb, smem, acc);
  const int lane = threadIdx.x & 63, w = threadIdx.x >> 6;
  const int r0 = mb * 128 + (w >> 1) * 64 + ((lane >> 4) << 2);
  const int c0 = nb * 128 + (w & 1) * 64 + (lane & 15);
#pragma unroll
  for (int i = 0; i < 4; ++i)
#pragma unroll
    for (int j = 0; j < 4; ++j)
#pragma unroll
      for (int e = 0; e < 4; ++e) {
        int row = r0 + i * 16 + e;
        int col = c0 + j * 16;
        float v = acc[i][j][e] + bias[col];
        float gl = 0.5f * v * (1.f + erff(v * 0.70710678118654752f));
        h3[(size_t)row * 1536 + col] = bf16bits(gl);
      }
}

// fc2: [25088,1536]x[1536,384] + bias; out += mlp
__global__ __launch_bounds__(256) void fc2_gemm(const u16* __restrict__ A,
                                                const u16* __restrict__ Bt,
                                                const float* __restrict__ bias,
                                                float* __restrict__ out,
                                                int row_base) {
  __shared__ char smem[32768];
  const int mb = blockIdx.x % 196, nb = blockIdx.x / 196;
  f32x4 acc[4][4];
  gemm_core(A, Bt, 1536, mb, nb, smem, acc);
  const int lane = threadIdx.x & 63, w = threadIdx.x >> 6;
  const int r0 = mb * 128 + (w >> 1) * 64 + ((lane >> 4) << 2);
  const int c0 = nb * 128 + (w & 1) * 64 + (lane & 15);
#pragma unroll
  for (int i = 0; i < 4; ++i)
#pragma unroll
    for (int j = 0; j < 4; ++j)
#pragma unroll
      for (int e = 0; e < 4; ++e) {
        int row = r0 + i * 16 + e;
        int col = c0 + j * 16;
        float v = acc[i][j][e] + bias[col];
        size_t gi = (size_t)(row_base + row) * 384 + col;
        out[gi] += v;
      }
}

// ---------------------------------------------------------------------------
extern "C" void kernel_launch(void* const* d_in, const int* in_sizes, int n_in,
                              void* d_out, int out_size, void* d_ws, size_t ws_size,
                              hipStream_t stream) {
  const float* x      = (const float*)d_in[0];
  const float* n1g    = (const float*)d_in[1];
  const float* n1b    = (const float*)d_in[2];
  const float* qkv_w  = (const float*)d_in[3];
  const float* qkv_b  = (const float*)d_in[4];
  const float* rpb    = (const float*)d_in[5];
  const float* proj_w = (const float*)d_in[6];
  const float* proj_b = (const float*)d_in[7];
  const float* n2g    = (const float*)d_in[8];
  const float* n2b    = (const float*)d_in[9];
  const float* fc1_w  = (const float*)d_in[10];
  const float* fc1_b  = (const float*)d_in[11];
  const float* fc2_w  = (const float*)d_in[12];
  const float* fc2_b  = (const float*)d_in[13];
  float* out = (float*)d_out;

  char* ws = (char*)d_ws;
  const size_t S = (size_t)50176 * 384 * 2;   // 38.5 MB (one bf16 [50176,384])
  u16* xw  = (u16*)ws;                        // LN1 out; later attn output o
  u16* qb  = (u16*)(ws + S);
  u16* kb  = (u16*)(ws + 2 * S);
  u16* vb  = (u16*)(ws + 3 * S);
  u16* h2  = (u16*)(ws + 4 * S);
  u16* h3  = (u16*)(ws + S);                  // aliases q+k (dead after attention)
  float* bias_t = (float*)(ws + 4 * S);       // aliases h2 (free during attention)
  u16* wqt  = (u16*)(ws + 5 * S);             // transposed bf16 weights (~3.5 MB)
  u16* wpt  = wqt  + 384 * 1152;
  u16* wf1t = wpt  + 384 * 384;
  u16* wf2t = wf1t + 384 * 1536;

  wtrans<<<(384 * 1152 + 255) / 256, 256, 0, stream>>>(qkv_w, wqt, 384, 1152);
  wtrans<<<(384 * 384  + 255) / 256, 256, 0, stream>>>(proj_w, wpt, 384, 384);
  wtrans<<<(384 * 1536 + 255) / 256, 256, 0, stream>>>(fc1_w, wf1t, 384, 1536);
  wtrans<<<(1536 * 384 + 255) / 256, 256, 0, stream>>>(fc2_w, wf2t, 1536, 384);
  gen_bias<<<768, 256, 0, stream>>>(rpb, bias_t);

  ln1_win<<<12544, 256, 0, stream>>>(x, n1g, n1b, xw);
  qkv_gemm<<<392 * 9, 256, 0, stream>>>(xw, wqt, qkv_b, qb, kb, vb);
  attn2<<<6144, 128, 0, stream>>>(qb, kb, vb, bias_t, xw);
  proj_gemm<<<392 * 3, 256, 0, stream>>>(xw, wpt, proj_b, x, out);
  ln2_kernel<<<12544, 256, 0, stream>>>(out, n2g, n2b, h2);
  for (int ch = 0; ch < 2; ++ch) {
    fc1_gemm<<<196 * 12, 256, 0, stream>>>(h2 + (size_t)ch * 25088 * 384, wf1t, fc1_b, h3);
    fc2_gemm<<<196 * 3, 256, 0, stream>>>(h3, wf2t, fc2_b, out, ch * 25088);
  }
}

// Round 3
// 491.112 us; speedup vs baseline: 1.3062x; 1.1386x over previous
//
#include <hip/hip_runtime.h>
#include <cstdint>
#include <cstddef>

using u16 = unsigned short;
using u32 = unsigned int;

typedef __bf16 bf16x8 __attribute__((ext_vector_type(8)));
typedef float f32x4 __attribute__((ext_vector_type(4)));

#define AS1 __attribute__((address_space(1)))
#define AS3 __attribute__((address_space(3)))

__device__ __forceinline__ void gload16(const void* g, void* l) {
  __builtin_amdgcn_global_load_lds((const AS1 u32*)g, (AS3 u32*)l, 16, 0, 0);
}

__device__ __forceinline__ u16 bf16bits(float f) {
  u32 u = __float_as_uint(f);
  u32 r = (u + 0x7fffu + ((u >> 16) & 1u)) >> 16;
  return (u16)r;
}

// XCD-chunked bijective block remap (m204): round-robin bid -> contiguous
// per-XCD work ranges; nb (fast axis) varies first so consecutive blocks on
// one XCD share the same A-tile (L2-resident).
__device__ __forceinline__ void xcd_tile(int bid, int nwg, int nfast,
                                         int& mb, int& nb) {
  int q = nwg >> 3, r = nwg & 7;
  int xcd = bid & 7, idx = bid >> 3;
  int nid = (xcd < r ? xcd * (q + 1) : r * (q + 1) + (xcd - r) * q) + idx;
  nb = nid % nfast;
  mb = nid / nfast;
}

// ---------------------------------------------------------------------------
// Generic bf16 GEMM core: C[128,128] tile of A[M,K] * Bt[N,K]^T, BK=64.
// 256 threads = 4 waves (2x2), each wave 64x64 via 4x4 frags of 16x16x32 MFMA.
// ---------------------------------------------------------------------------
__device__ __forceinline__ void gemm_core(const u16* __restrict__ A,
                                          const u16* __restrict__ Bt,
                                          int K, int mb, int nb,
                                          char* smem, f32x4 (&acc)[4][4]) {
  const int tid = threadIdx.x;
  const int lane = tid & 63;
  const int w = tid >> 6;
  const int wr = w >> 1, wc = w & 1;
  char* As = smem;
  char* Bs = smem + 16384;

  const int trow = tid >> 3;                 // 0..31 (row within 32-row stripe)
  const int gsw = (tid & 7) ^ (trow & 7);    // pre-swizzled source chunk

  const u16* ga[4]; const u16* gb[4];
  char* la[4]; char* lb[4];
#pragma unroll
  for (int i = 0; i < 4; ++i) {
    int row = i * 32 + trow;
    ga[i] = A  + (size_t)(mb * 128 + row) * K + gsw * 8;
    gb[i] = Bt + (size_t)(nb * 128 + row) * K + gsw * 8;
    la[i] = As + i * 4096 + w * 1024;
    lb[i] = Bs + i * 4096 + w * 1024;
  }
#pragma unroll
  for (int i = 0; i < 4; ++i)
#pragma unroll
    for (int j = 0; j < 4; ++j)
      acc[i][j] = f32x4{0.f, 0.f, 0.f, 0.f};

  int aoff[2][4], boff[2][4];
#pragma unroll
  for (int kk = 0; kk < 2; ++kk)
#pragma unroll
    for (int t = 0; t < 4; ++t) {
      int ra = wr * 64 + t * 16 + (lane & 15);
      aoff[kk][t] = ra * 128 + (((kk * 4 + (lane >> 4)) ^ (ra & 7)) << 4);
      int rb = wc * 64 + t * 16 + (lane & 15);
      boff[kk][t] = rb * 128 + (((kk * 4 + (lane >> 4)) ^ (rb & 7)) << 4);
    }

  const int nk = K >> 6;
  for (int kt = 0; kt < nk; ++kt) {
#pragma unroll
    for (int i = 0; i < 4; ++i) gload16(ga[i], la[i]);
#pragma unroll
    for (int i = 0; i < 4; ++i) gload16(gb[i], lb[i]);
#pragma unroll
    for (int i = 0; i < 4; ++i) { ga[i] += 64; gb[i] += 64; }
    __syncthreads();
#pragma unroll
    for (int kk = 0; kk < 2; ++kk) {
      bf16x8 af[4], bfr[4];
#pragma unroll
      for (int t = 0; t < 4; ++t) af[t]  = *(const bf16x8*)(As + aoff[kk][t]);
#pragma unroll
      for (int t = 0; t < 4; ++t) bfr[t] = *(const bf16x8*)(Bs + boff[kk][t]);
#pragma unroll
      for (int i = 0; i < 4; ++i)
#pragma unroll
        for (int j = 0; j < 4; ++j)
          acc[i][j] = __builtin_amdgcn_mfma_f32_16x16x32_bf16(af[i], bfr[j], acc[i][j], 0, 0, 0);
    }
    __syncthreads();
  }
}

// ---------------------------------------------------------------------------
// Weight transpose + bf16 cast: W[K][N] f32 -> Wt[N][K] bf16
// ---------------------------------------------------------------------------
__global__ void wtrans(const float* __restrict__ W, u16* __restrict__ Wt, int K, int N) {
  int idx = blockIdx.x * 256 + threadIdx.x;
  if (idx < K * N) {
    int n = idx / K, k = idx - n * K;
    Wt[idx] = bf16bits(W[(size_t)k * N + n]);
  }
}

// ---------------------------------------------------------------------------
// Fused bias+mask table: bt[cls][head][row][col], 4*12*64*64 f32.
// cls = (wi==7)*2 + (wj==7).  rows/cols >= 49 -> -1e30.
// ---------------------------------------------------------------------------
__global__ void gen_bias(const float* __restrict__ rpb, float* __restrict__ bt) {
  int idx = blockIdx.x * 256 + threadIdx.x;
  if (idx >= 4 * 12 * 4096) return;
  int col = idx & 63, row = (idx >> 6) & 63;
  int rest = idx >> 12;
  int h = rest % 12, cls = rest / 12;
  float v;
  if (row >= 49 || col >= 49) {
    v = -1e30f;
  } else {
    int qr = row / 7, qc = row - qr * 7;
    int kr = col / 7, kc = col - kr * 7;
    v = rpb[((qr - kr + 6) * 13 + (qc - kc + 6)) * 12 + h];
    bool wi7 = (cls & 2) != 0, wj7 = (cls & 1) != 0;
    int idq = (wi7 ? (qr < 4 ? 3 : 6) : 0) + (wj7 ? (qc < 4 ? 1 : 2) : 0);
    int idk = (wi7 ? (kr < 4 ? 3 : 6) : 0) + (wj7 ? (kc < 4 ? 1 : 2) : 0);
    if (idq != idk) v += -100.f;
  }
  bt[idx] = v;
}

// ---------------------------------------------------------------------------
// LN1 fused with roll(-3,-3) + window partition gather.  One wave per out row.
// ---------------------------------------------------------------------------
__global__ __launch_bounds__(256) void ln1_win(const float* __restrict__ x,
                                               const float* __restrict__ g,
                                               const float* __restrict__ b,
                                               u16* __restrict__ xw) {
  const int lane = threadIdx.x & 63;
  const int w = threadIdx.x >> 6;
  const int row = blockIdx.x * 4 + w;
  const int win = row / 49, tok = row - win * 49;
  const int bimg = win >> 6, wloc = win & 63, wi = wloc >> 3, wj = wloc & 7;
  const int r = tok / 7, cc = tok - r * 7;
  const int ho = (wi * 7 + r + 3) % 56;
  const int wo = (wj * 7 + cc + 3) % 56;
  const float* src = x + ((size_t)bimg * 3136 + ho * 56 + wo) * 384;
  float v[6]; float s = 0.f, s2 = 0.f;
#pragma unroll
  for (int i = 0; i < 6; ++i) { float t = src[lane + i * 64]; v[i] = t; s += t; s2 += t * t; }
#pragma unroll
  for (int o = 1; o < 64; o <<= 1) { s += __shfl_xor(s, o); s2 += __shfl_xor(s2, o); }
  float mu = s * (1.f / 384.f);
  float rs = rsqrtf(s2 * (1.f / 384.f) - mu * mu + 1e-5f);
  u16* dst = xw + (size_t)row * 384;
#pragma unroll
  for (int i = 0; i < 6; ++i) {
    int c = lane + i * 64;
    dst[c] = bf16bits((v[i] - mu) * rs * g[c] + b[c]);
  }
}

// LN2: identity row mapping, reads x2 (f32, in d_out), writes bf16
__global__ __launch_bounds__(256) void ln2_kernel(const float* __restrict__ xin,
                                                  const float* __restrict__ g,
                                                  const float* __restrict__ b,
                                                  u16* __restrict__ h2) {
  const int lane = threadIdx.x & 63;
  const int w = threadIdx.x >> 6;
  const int row = blockIdx.x * 4 + w;
  const float* src = xin + (size_t)row * 384;
  float v[6]; float s = 0.f, s2 = 0.f;
#pragma unroll
  for (int i = 0; i < 6; ++i) { float t = src[lane + i * 64]; v[i] = t; s += t; s2 += t * t; }
#pragma unroll
  for (int o = 1; o < 64; o <<= 1) { s += __shfl_xor(s, o); s2 += __shfl_xor(s2, o); }
  float mu = s * (1.f / 384.f);
  float rs = rsqrtf(s2 * (1.f / 384.f) - mu * mu + 1e-5f);
  u16* dst = h2 + (size_t)row * 384;
#pragma unroll
  for (int i = 0; i < 6; ++i) {
    int c = lane + i * 64;
    dst[c] = bf16bits((v[i] - mu) * rs * g[c] + b[c]);
  }
}

// ---------------------------------------------------------------------------
// QKV GEMM: [50176,384]x[384,1152] + bias -> row-major [50176][1152] bf16.
// q columns (nb<3) pre-scaled by 1/sqrt(32).  No divisions in epilogue.
// ---------------------------------------------------------------------------
__global__ __launch_bounds__(256) void qkv_gemm(const u16* __restrict__ A,
                                                const u16* __restrict__ Bt,
                                                const float* __restrict__ bias,
                                                u16* __restrict__ qkvb) {
  __shared__ char smem[32768];
  int mb, nb;
  xcd_tile(blockIdx.x, 3528, 9, mb, nb);
  f32x4 acc[4][4];
  gemm_core(A, Bt, 384, mb, nb, smem, acc);
  const int lane = threadIdx.x & 63, w = threadIdx.x >> 6;
  const int r0 = mb * 128 + (w >> 1) * 64 + ((lane >> 4) << 2);
  const int c0 = nb * 128 + (w & 1) * 64 + (lane & 15);
  const float qs = (nb < 3) ? 0.17677669529663687f : 1.0f;
  float bj[4];
#pragma unroll
  for (int j = 0; j < 4; ++j) bj[j] = bias[c0 + j * 16];
#pragma unroll
  for (int i = 0; i < 4; ++i)
#pragma unroll
    for (int e = 0; e < 4; ++e) {
      int row = r0 + i * 16 + e;
      u16* dst = qkvb + (size_t)row * 1152 + c0;
#pragma unroll
      for (int j = 0; j < 4; ++j)
        dst[j * 16] = bf16bits((acc[i][j][e] + bj[j]) * qs);
    }
}

// ---------------------------------------------------------------------------
// Attention v2: 128 threads = 2 independent waves, each one (win,head).
// Q/K/V read from row-major qkv buffer [win*49+tok][1152].
// LDS per wave: vt [32][136B] + P [64][136B] = 12.75KB.
// ---------------------------------------------------------------------------
__global__ __launch_bounds__(128, 3) void attn2(const u16* __restrict__ qkvb,
                                                const float* __restrict__ bt,
                                                u16* __restrict__ ob) {
  __shared__ char smem[26112];
  const int wv = threadIdx.x >> 6, lane = threadIdx.x & 63;
  char* vts = smem + wv * 13056;          // [32 d][136B]
  char* ps  = smem + wv * 13056 + 4352;   // [64 q][136B]
  const int p = blockIdx.x * 2 + wv;
  const int win = p / 12, head = p - win * 12;
  const int wloc = win & 63, wi = wloc >> 3, wj = wloc & 7;
  const int cls = ((wi == 7) ? 2 : 0) + ((wj == 7) ? 1 : 0);

  // zero vt (so P*0 stays clean for tok>=49)
#pragma unroll
  for (int i = 0; i < 17; ++i) ((u32*)vts)[lane + i * 64] = 0;

  const u16* qg = qkvb + (size_t)win * 49 * 1152 + head * 32;
  const u16* kg = qg + 384;
  const u16* vg = qg + 768;
  // V transpose into LDS: vt[d][tok]
#pragma unroll
  for (int it = 0; it < 4; ++it) {
    int c = lane + it * 64;
    if (c < 196) {
      int tok = c >> 2, d0 = (c & 3) * 8;
      union { uint4 v; u16 h[8]; } u;
      u.v = *(const uint4*)(vg + (size_t)tok * 1152 + d0);
#pragma unroll
      for (int jj = 0; jj < 8; ++jj)
        *(u16*)(vts + (d0 + jj) * 136 + tok * 2) = u.h[jj];
    }
  }

  const int rsel = lane & 15;
  const int ksub = lane >> 4;
  // Q/K fragments direct from global, predicated
  bf16x8 aq[4], bk[4];
#pragma unroll
  for (int t = 0; t < 4; ++t) {
    int row = t * 16 + rsel;
    union { uint4 u; bf16x8 v; } rq, rk;
    if (row < 49) {
      rq.u = *(const uint4*)(qg + (size_t)row * 1152 + ksub * 8);
      rk.u = *(const uint4*)(kg + (size_t)row * 1152 + ksub * 8);
    } else {
      rq.u = uint4{0, 0, 0, 0};
      rk.u = uint4{0, 0, 0, 0};
    }
    aq[t] = rq.v; bk[t] = rk.v;
  }

  // S = q k^T
  f32x4 s[4][4];
#pragma unroll
  for (int i = 0; i < 4; ++i)
#pragma unroll
    for (int j = 0; j < 4; ++j) s[i][j] = f32x4{0.f, 0.f, 0.f, 0.f};
#pragma unroll
  for (int i = 0; i < 4; ++i)
#pragma unroll
    for (int j = 0; j < 4; ++j)
      s[i][j] = __builtin_amdgcn_mfma_f32_16x16x32_bf16(aq[i], bk[j], s[i][j], 0, 0, 0);

  // softmax with fused bias+mask table
  const float* tb = bt + ((size_t)(cls * 12 + head) << 12);
  const int rowsub = ksub << 2;
#pragma unroll
  for (int i = 0; i < 4; ++i) {
    float bl[4][4];
#pragma unroll
    for (int e = 0; e < 4; ++e) {
      int row = i * 16 + rowsub + e;
#pragma unroll
      for (int j = 0; j < 4; ++j) bl[e][j] = tb[row * 64 + j * 16 + rsel];
    }
#pragma unroll
    for (int e = 0; e < 4; ++e) {
      int row = i * 16 + rowsub + e;
      float v[4];
#pragma unroll
      for (int j = 0; j < 4; ++j) v[j] = s[i][j][e] + bl[e][j];
      float m = fmaxf(fmaxf(v[0], v[1]), fmaxf(v[2], v[3]));
#pragma unroll
      for (int o = 1; o < 16; o <<= 1) m = fmaxf(m, __shfl_xor(m, o));
      float pr[4]; float sum = 0.f;
#pragma unroll
      for (int j = 0; j < 4; ++j) { pr[j] = __expf(v[j] - m); sum += pr[j]; }
#pragma unroll
      for (int o = 1; o < 16; o <<= 1) sum += __shfl_xor(sum, o);
      float inv = 1.f / sum;
#pragma unroll
      for (int j = 0; j < 4; ++j)
        *(u16*)(ps + row * 136 + (j * 16 + rsel) * 2) = bf16bits(pr[j] * inv);
    }
  }

  // O = P V
  f32x4 o[4][2];
#pragma unroll
  for (int i = 0; i < 4; ++i)
#pragma unroll
    for (int j = 0; j < 2; ++j) o[i][j] = f32x4{0.f, 0.f, 0.f, 0.f};
#pragma unroll
  for (int kk = 0; kk < 2; ++kk) {
    bf16x8 ap[4], bv[2];
#pragma unroll
    for (int t = 0; t < 4; ++t)
      ap[t] = *(const bf16x8*)(ps + (t * 16 + rsel) * 136 + kk * 64 + ksub * 16);
#pragma unroll
    for (int t = 0; t < 2; ++t)
      bv[t] = *(const bf16x8*)(vts + (t * 16 + rsel) * 136 + kk * 64 + ksub * 16);
#pragma unroll
    for (int i = 0; i < 4; ++i)
#pragma unroll
      for (int j = 0; j < 2; ++j)
        o[i][j] = __builtin_amdgcn_mfma_f32_16x16x32_bf16(ap[i], bv[j], o[i][j], 0, 0, 0);
  }

  u16* obase = ob + (size_t)win * 49 * 384 + head * 32;
#pragma unroll
  for (int i = 0; i < 4; ++i)
#pragma unroll
    for (int j = 0; j < 2; ++j)
#pragma unroll
      for (int e = 0; e < 4; ++e) {
        int tok = i * 16 + rowsub + e;
        if (tok < 49)
          obase[(size_t)tok * 384 + j * 16 + rsel] = bf16bits(o[i][j][e]);
      }
}

// ---------------------------------------------------------------------------
// proj GEMM: [50176,384]x[384,384] + bias; window-reverse + roll-back scatter
// + shortcut add -> x2 (f32, in d_out).  Row-index math hoisted per (i,e).
// ---------------------------------------------------------------------------
__global__ __launch_bounds__(256) void proj_gemm(const u16* __restrict__ A,
                                                 const u16* __restrict__ Bt,
                                                 const float* __restrict__ bias,
                                                 const float* __restrict__ xres,
                                                 float* __restrict__ out) {
  __shared__ char smem[32768];
  int mb, nb;
  xcd_tile(blockIdx.x, 1176, 3, mb, nb);
  f32x4 acc[4][4];
  gemm_core(A, Bt, 384, mb, nb, smem, acc);
  const int lane = threadIdx.x & 63, w = threadIdx.x >> 6;
  const int r0 = mb * 128 + (w >> 1) * 64 + ((lane >> 4) << 2);
  const int c0 = nb * 128 + (w & 1) * 64 + (lane & 15);
  float bj[4];
#pragma unroll
  for (int j = 0; j < 4; ++j) bj[j] = bias[c0 + j * 16];
#pragma unroll
  for (int i = 0; i < 4; ++i)
#pragma unroll
    for (int e = 0; e < 4; ++e) {
      int row = r0 + i * 16 + e;
      int wn = row / 49, tok = row - wn * 49;
      int bimg = wn >> 6, wloc = wn & 63, wi = wloc >> 3, wj = wloc & 7;
      int r = tok / 7, cc = tok - r * 7;
      int t1 = wi * 7 + r + 3;  int ho = t1 >= 56 ? t1 - 56 : t1;
      int t2 = wj * 7 + cc + 3; int wo = t2 >= 56 ? t2 - 56 : t2;
      size_t gbase = ((size_t)bimg * 3136 + ho * 56 + wo) * 384 + c0;
#pragma unroll
      for (int j = 0; j < 4; ++j) {
        size_t gi = gbase + j * 16;
        out[gi] = acc[i][j][e] + bj[j] + xres[gi];
      }
    }
}

// fc1: [25088,384]x[384,1536] + bias + exact GELU -> bf16
__global__ __launch_bounds__(256) void fc1_gemm(const u16* __restrict__ A,
                                                const u16* __restrict__ Bt,
                                                const float* __restrict__ bias,
                                                u16* __restrict__ h3) {
  __shared__ char smem[32768];
  int mb, nb;
  xcd_tile(blockIdx.x, 2352, 12, mb, nb);
  f32x4 acc[4][4];
  gemm_core(A, Bt, 384, mb, nb, smem, acc);
  const int lane = threadIdx.x & 63, w = threadIdx.x >> 6;
  const int r0 = mb * 128 + (w >> 1) * 64 + ((lane >> 4) << 2);
  const int c0 = nb * 128 + (w & 1) * 64 + (lane & 15);
  float bj[4];
#pragma unroll
  for (int j = 0; j < 4; ++j) bj[j] = bias[c0 + j * 16];
#pragma unroll
  for (int i = 0; i < 4; ++i)
#pragma unroll
    for (int e = 0; e < 4; ++e) {
      int row = r0 + i * 16 + e;
      u16* dst = h3 + (size_t)row * 1536 + c0;
#pragma unroll
      for (int j = 0; j < 4; ++j) {
        float v = acc[i][j][e] + bj[j];
        float gl = 0.5f * v * (1.f + erff(v * 0.70710678118654752f));
        dst[j * 16] = bf16bits(gl);
      }
    }
}

// fc2: [25088,1536]x[1536,384] + bias; out += mlp
__global__ __launch_bounds__(256) void fc2_gemm(const u16* __restrict__ A,
                                                const u16* __restrict__ Bt,
                                                const float* __restrict__ bias,
                                                float* __restrict__ out,
                                                int row_base) {
  __shared__ char smem[32768];
  int mb, nb;
  xcd_tile(blockIdx.x, 588, 3, mb, nb);
  f32x4 acc[4][4];
  gemm_core(A, Bt, 1536, mb, nb, smem, acc);
  const int lane = threadIdx.x & 63, w = threadIdx.x >> 6;
  const int r0 = mb * 128 + (w >> 1) * 64 + ((lane >> 4) << 2);
  const int c0 = nb * 128 + (w & 1) * 64 + (lane & 15);
  float bj[4];
#pragma unroll
  for (int j = 0; j < 4; ++j) bj[j] = bias[c0 + j * 16];
#pragma unroll
  for (int i = 0; i < 4; ++i)
#pragma unroll
    for (int e = 0; e < 4; ++e) {
      int row = r0 + i * 16 + e;
      float* dst = out + (size_t)(row_base + row) * 384 + c0;
#pragma unroll
      for (int j = 0; j < 4; ++j)
        dst[j * 16] += acc[i][j][e] + bj[j];
    }
}

// ---------------------------------------------------------------------------
extern "C" void kernel_launch(void* const* d_in, const int* in_sizes, int n_in,
                              void* d_out, int out_size, void* d_ws, size_t ws_size,
                              hipStream_t stream) {
  const float* x      = (const float*)d_in[0];
  const float* n1g    = (const float*)d_in[1];
  const float* n1b    = (const float*)d_in[2];
  const float* qkv_w  = (const float*)d_in[3];
  const float* qkv_b  = (const float*)d_in[4];
  const float* rpb    = (const float*)d_in[5];
  const float* proj_w = (const float*)d_in[6];
  const float* proj_b = (const float*)d_in[7];
  const float* n2g    = (const float*)d_in[8];
  const float* n2b    = (const float*)d_in[9];
  const float* fc1_w  = (const float*)d_in[10];
  const float* fc1_b  = (const float*)d_in[11];
  const float* fc2_w  = (const float*)d_in[12];
  const float* fc2_b  = (const float*)d_in[13];
  float* out = (float*)d_out;

  char* ws = (char*)d_ws;
  const size_t S = (size_t)50176 * 384 * 2;   // 38.5 MB (one bf16 [50176,384])
  u16* xw   = (u16*)ws;                       // LN1 out; later attn output o
  u16* qkvb = (u16*)(ws + S);                 // [50176][1152] bf16 (3S)
  u16* h2   = (u16*)(ws + 4 * S);
  u16* h3   = (u16*)(ws + S);                 // aliases qkvb (dead after attn)
  float* bias_t = (float*)(ws + 4 * S);       // aliases h2 (free during attn)
  u16* wqt  = (u16*)(ws + 5 * S);             // transposed bf16 weights (~3.5 MB)
  u16* wpt  = wqt  + 384 * 1152;
  u16* wf1t = wpt  + 384 * 384;
  u16* wf2t = wf1t + 384 * 1536;

  wtrans<<<(384 * 1152 + 255) / 256, 256, 0, stream>>>(qkv_w, wqt, 384, 1152);
  wtrans<<<(384 * 384  + 255) / 256, 256, 0, stream>>>(proj_w, wpt, 384, 384);
  wtrans<<<(384 * 1536 + 255) / 256, 256, 0, stream>>>(fc1_w, wf1t, 384, 1536);
  wtrans<<<(1536 * 384 + 255) / 256, 256, 0, stream>>>(fc2_w, wf2t, 1536, 384);
  gen_bias<<<768, 256, 0, stream>>>(rpb, bias_t);

  ln1_win<<<12544, 256, 0, stream>>>(x, n1g, n1b, xw);
  qkv_gemm<<<3528, 256, 0, stream>>>(xw, wqt, qkv_b, qkvb);
  attn2<<<6144, 128, 0, stream>>>(qkvb, bias_t, xw);
  proj_gemm<<<1176, 256, 0, stream>>>(xw, wpt, proj_b, x, out);
  ln2_kernel<<<12544, 256, 0, stream>>>(out, n2g, n2b, h2);
  for (int ch = 0; ch < 2; ++ch) {
    fc1_gemm<<<2352, 256, 0, stream>>>(h2 + (size_t)ch * 25088 * 384, wf1t, fc1_b, h3);
    fc2_gemm<<<588, 256, 0, stream>>>(h3, wf2t, fc2_b, out, ch * 25088);
  }
}